// Round 4
// baseline (244.255 us; speedup 1.0000x reference)
//
#include <hip/hip_runtime.h>
#include <math.h>

#define N_NODES 200000
#define N_VAR   112000
#define N_EDGES 3200000
#define NB_SCAN 782           // ceil(200000/256)
#define CAP     64            // padded row capacity (P(deg>=64)~1e-24)

// ---- two-level counting-sort params ----
#define NFINE    512          // fine dst-range buckets
#define PSZ_F    391          // nodes per bucket (512*391 = 200192 >= 200000)
#define FCAP     7168         // per-bucket edge capacity (mean 6250, ~11.6 sigma slack)
#define BIN_CHUNK 8192        // edges per k_bin block
#define NB_BIN   391          // ceil(3.2e6/8192)

typedef int v4i __attribute__((ext_vector_type(4)));

__device__ __forceinline__ float bcast_lane(float x, int lane) {
    return __int_as_float(__builtin_amdgcn_readlane(__float_as_int(x), lane));
}

// ---------- setup: zero bcnt + fold Wc = W2@Wfc, bc ----------
__global__ void __launch_bounds__(256) k_setup(const float* __restrict__ W2,
                                               const float* __restrict__ b2,
                                               const float* __restrict__ Wfc,
                                               const float* __restrict__ bfc,
                                               float* __restrict__ Wc,
                                               float* __restrict__ bc,
                                               int* __restrict__ bcnt) {
    int b = blockIdx.x;
    int i = b * 256 + threadIdx.x;
    if (i < NFINE) bcnt[i] = 0;
    if (b < 16) {
        int e = b * 256 + threadIdx.x;     // 4096 entries
        int j = e >> 6, l = e & 63;
        double acc = 0.0;
        for (int m = 0; m < 64; ++m)
            acc += (double)W2[j * 64 + m] * (double)Wfc[m * 64 + l];
        Wc[e] = (float)acc;
    } else if (b == 16 && threadIdx.x < 64) {
        int l = threadIdx.x;
        double acc = (double)bfc[l];
        for (int m = 0; m < 64; ++m)
            acc += (double)b2[m] * (double)Wfc[m * 64 + l];
        bc[l] = (float)acc;
    }
}

// ---------- phase A: bin edges into 512 dst-range buckets ----------
// Packed entry: (dst_local<<18 | src), dst_local<391 (9b), src<2^18.
__global__ void __launch_bounds__(512) k_bin(const int* __restrict__ src,
                                             const int* __restrict__ dst,
                                             int* __restrict__ bins,
                                             int* __restrict__ bcnt) {
    __shared__ int hist[NFINE];
    __shared__ int seg[NFINE];
    __shared__ int gb[NFINE];
    __shared__ int cur[NFINE];
    __shared__ int scn[NFINE];
    __shared__ int stg[BIN_CHUNK];
    __shared__ unsigned short stgb[BIN_CHUNK];
    int tid = threadIdx.x;
    hist[tid] = 0;
    __syncthreads();

    int base = blockIdx.x * BIN_CHUNK;
    int pk[4][4];
    int bk[4][4];
    bool val[4];
    #pragma unroll
    for (int i = 0; i < 4; ++i) {
        int e4 = base + (i * 512 + tid) * 4;
        val[i] = (e4 < N_EDGES);
        if (val[i]) {
            v4i d = __builtin_nontemporal_load((const v4i*)(dst + e4));
            v4i s = __builtin_nontemporal_load((const v4i*)(src + e4));
            int dd[4] = {d.x, d.y, d.z, d.w};
            int ss[4] = {s.x, s.y, s.z, s.w};
            #pragma unroll
            for (int q = 0; q < 4; ++q) {
                int bb = dd[q] / PSZ_F;
                int dl = dd[q] - bb * PSZ_F;
                pk[i][q] = (dl << 18) | ss[q];
                bk[i][q] = bb;
                atomicAdd(&hist[bb], 1);
            }
        }
    }
    __syncthreads();

    scn[tid] = hist[tid];
    __syncthreads();
    for (int d = 1; d < NFINE; d <<= 1) {
        int t = scn[tid];
        int u = (tid >= d) ? scn[tid - d] : 0;
        __syncthreads();
        scn[tid] = t + u;
        __syncthreads();
    }
    int ex = scn[tid] - hist[tid];
    seg[tid] = ex;
    cur[tid] = ex;
    gb[tid]  = atomicAdd(&bcnt[tid], hist[tid]);
    __syncthreads();
    int tot = scn[NFINE - 1];

    #pragma unroll
    for (int i = 0; i < 4; ++i) {
        if (val[i]) {
            #pragma unroll
            for (int q = 0; q < 4; ++q) {
                int p = atomicAdd(&cur[bk[i][q]], 1);
                stg[p]  = pk[i][q];
                stgb[p] = (unsigned short)bk[i][q];
            }
        }
    }
    __syncthreads();

    for (int i = tid; i < tot; i += 512) {
        int bb  = stgb[i];
        int pos = gb[bb] + (i - seg[bb]);
        if (pos < FCAP)
            bins[(size_t)bb * FCAP + pos] = stg[i];
    }
}

// ---------- phase B: per-bucket counting sort -> exact cnt + coalesced buf rows ----------
__global__ void __launch_bounds__(512) k_sort(const int* __restrict__ bins,
                                              const int* __restrict__ bcnt,
                                              int* __restrict__ cnt,
                                              int* __restrict__ buf) {
    __shared__ int hist[NFINE];
    __shared__ int scn[NFINE];
    __shared__ int off[NFINE];
    __shared__ int cur[NFINE];
    __shared__ int sorted[FCAP];
    __shared__ unsigned short rowid[FCAP];
    int tid = threadIdx.x;
    int b = blockIdx.x;
    int n = bcnt[b];
    if (n > FCAP) n = FCAP;
    const int* __restrict__ bp = bins + (size_t)b * FCAP;

    hist[tid] = 0;
    __syncthreads();
    for (int i = tid; i < n; i += 512)
        atomicAdd(&hist[bp[i] >> 18], 1);
    __syncthreads();

    int v = b * PSZ_F + tid;
    if (tid < PSZ_F && v < N_NODES) cnt[v] = hist[tid];

    scn[tid] = hist[tid];
    __syncthreads();
    for (int d = 1; d < NFINE; d <<= 1) {
        int t = scn[tid];
        int u = (tid >= d) ? scn[tid - d] : 0;
        __syncthreads();
        scn[tid] = t + u;
        __syncthreads();
    }
    int ex = scn[tid] - hist[tid];
    off[tid] = ex;
    cur[tid] = ex;
    __syncthreads();

    for (int i = tid; i < n; i += 512) {
        int pk = bp[i];
        int dl = pk >> 18;
        int p = atomicAdd(&cur[dl], 1);
        sorted[p] = pk & 0x3FFFF;
        rowid[p]  = (unsigned short)dl;
    }
    __syncthreads();

    for (int i = tid; i < n; i += 512) {
        int dl = rowid[i];
        int slot = i - off[dl];
        if (slot < CAP)
            buf[(size_t)(b * PSZ_F + dl) * CAP + slot] = sorted[i];
    }
}

// ---------- post: xdc[v] = (xn.x, xn.y, dv, 0) ----------
__global__ void __launch_bounds__(256) k_post(const int* __restrict__ cnt,
                                              const float2* __restrict__ x2,
                                              float4* __restrict__ xdc) {
    int i = blockIdx.x * 256 + threadIdx.x;
    if (i >= N_NODES) return;
    float dv = rsqrtf((float)cnt[i] + 1.0f);
    float2 xv = x2[i];
    xdc[i] = make_float4(xv.x * dv, xv.y * dv, dv, 0.0f);
}

// ---------- layer 1: zn[v] = (i0, i1, dv, 0) -- f32 partial accumulators ----------
__global__ void __launch_bounds__(256) k_l1a(const int* __restrict__ cnt,
                                             const int* __restrict__ buf,
                                             const float4* __restrict__ xdc,
                                             float4* __restrict__ zn) {
    int v = blockIdx.x * 256 + threadIdx.x;
    if (v >= N_NODES) return;
    int c = cnt[v];
    int n = (c < CAP) ? c : CAP;
    const int* __restrict__ rowp = buf + v * CAP;
    float4 self = xdc[v];
    float dv = self.z;
    float ax = self.x, ay = self.y;
    float bx = 0.0f,   by = 0.0f;
    int j = 0;
    for (; j + 16 <= n; j += 16) {
        v4i r0 = *(const v4i*)(rowp + j);
        v4i r1 = *(const v4i*)(rowp + j + 4);
        v4i r2 = *(const v4i*)(rowp + j + 8);
        v4i r3 = *(const v4i*)(rowp + j + 12);
        float4 p0 = xdc[r0.x], p1 = xdc[r0.y], p2 = xdc[r0.z], p3 = xdc[r0.w];
        float4 p4 = xdc[r1.x], p5 = xdc[r1.y], p6 = xdc[r1.z], p7 = xdc[r1.w];
        float4 p8 = xdc[r2.x], p9 = xdc[r2.y], pa = xdc[r2.z], pb = xdc[r2.w];
        float4 pc = xdc[r3.x], pd = xdc[r3.y], pe = xdc[r3.z], pf = xdc[r3.w];
        ax += p0.x; ay += p0.y;  bx += p1.x; by += p1.y;
        ax += p2.x; ay += p2.y;  bx += p3.x; by += p3.y;
        ax += p4.x; ay += p4.y;  bx += p5.x; by += p5.y;
        ax += p6.x; ay += p6.y;  bx += p7.x; by += p7.y;
        ax += p8.x; ay += p8.y;  bx += p9.x; by += p9.y;
        ax += pa.x; ay += pa.y;  bx += pb.x; by += pb.y;
        ax += pc.x; ay += pc.y;  bx += pd.x; by += pd.y;
        ax += pe.x; ay += pe.y;  bx += pf.x; by += pf.y;
    }
    for (; j + 8 <= n; j += 8) {
        v4i r0 = *(const v4i*)(rowp + j);
        v4i r1 = *(const v4i*)(rowp + j + 4);
        float4 p0 = xdc[r0.x], p1 = xdc[r0.y], p2 = xdc[r0.z], p3 = xdc[r0.w];
        float4 p4 = xdc[r1.x], p5 = xdc[r1.y], p6 = xdc[r1.z], p7 = xdc[r1.w];
        ax += p0.x; ay += p0.y;  bx += p1.x; by += p1.y;
        ax += p2.x; ay += p2.y;  bx += p3.x; by += p3.y;
        ax += p4.x; ay += p4.y;  bx += p5.x; by += p5.y;
        ax += p6.x; ay += p6.y;  bx += p7.x; by += p7.y;
    }
    for (; j < n; ++j) {
        int s = rowp[j];
        float4 p = xdc[s];
        ax += p.x; ay += p.y;
    }
    zn[v] = make_float4((ax + bx) * dv, (ay + by) * dv, dv, 0.0f);
}

// ---------- layer 2 + folded fc, var nodes only -- all-f32, zero LDS ----------
// FC: Wc column held in 64 VGPRs per lane (loaded once per block, coalesced,
// L2-hot); A broadcast via v_readlane (lane jj holds channel jj's aggregate).
// Replaces 64 ds_read_b32 + 16 ds_read_b128 per node with 64 readlane.
// No LDS, no barriers -> the 4 node-iterations pipeline freely.
__global__ void __launch_bounds__(256) k_l2(const int* __restrict__ cnt,
                                            const int* __restrict__ buf,
                                            const float4* __restrict__ zn,
                                            const float* __restrict__ W1,
                                            const float* __restrict__ b1,
                                            const float* __restrict__ Wc,
                                            const float* __restrict__ bc,
                                            float* __restrict__ out) {
    int w = threadIdx.x >> 6, l = threadIdx.x & 63;
    // per-lane Wc column: wc[j] = Wc[j][l]; 64 coalesced dword loads, once/block
    float wc[64];
    #pragma unroll
    for (int j = 0; j < 64; ++j)
        wc[j] = Wc[j * 64 + l];
    float w1a = W1[l], w1b = W1[64 + l], bb = b1[l];
    float bcl = bc[l];
    int v0 = blockIdx.x * 16 + w;          // wave w owns v0, v0+4, v0+8, v0+12
    int cA = __builtin_amdgcn_readfirstlane(cnt[v0]);
    int cB = __builtin_amdgcn_readfirstlane(cnt[v0 + 4]);
    int cC = __builtin_amdgcn_readfirstlane(cnt[v0 + 8]);
    int cD = __builtin_amdgcn_readfirstlane(cnt[v0 + 12]);

    #pragma unroll
    for (int it = 0; it < 4; ++it) {
        int v = v0 + it * 4;
        int c = (it == 0) ? cA : (it == 1) ? cB : (it == 2) ? cC : cD;
        int n = (c < CAP) ? c : CAP;
        float dv = rsqrtf((float)c + 1.0f);
        const int* __restrict__ row = buf + v * CAP;

        float4 zs = zn[v];                 // self (broadcast)
        float acc0 = fmaxf(fmaf(zs.x, w1a, fmaf(zs.y, w1b, bb)), 0.0f) * zs.z;
        float acc1 = 0.0f;
        int j = 0;
        for (; j + 8 <= n; j += 8) {
            v4i ra = *(const v4i*)(row + j);
            v4i rb = *(const v4i*)(row + j + 4);
            int s0 = __builtin_amdgcn_readfirstlane(ra.x);
            int s1 = __builtin_amdgcn_readfirstlane(ra.y);
            int s2 = __builtin_amdgcn_readfirstlane(ra.z);
            int s3 = __builtin_amdgcn_readfirstlane(ra.w);
            int s4 = __builtin_amdgcn_readfirstlane(rb.x);
            int s5 = __builtin_amdgcn_readfirstlane(rb.y);
            int s6 = __builtin_amdgcn_readfirstlane(rb.z);
            int s7 = __builtin_amdgcn_readfirstlane(rb.w);
            float4 p0 = zn[s0], p1 = zn[s1], p2 = zn[s2], p3 = zn[s3];
            float4 p4 = zn[s4], p5 = zn[s5], p6 = zn[s6], p7 = zn[s7];
            float h0 = fmaxf(fmaf(p0.x, w1a, fmaf(p0.y, w1b, bb)), 0.0f) * p0.z;
            float h1 = fmaxf(fmaf(p1.x, w1a, fmaf(p1.y, w1b, bb)), 0.0f) * p1.z;
            float h2 = fmaxf(fmaf(p2.x, w1a, fmaf(p2.y, w1b, bb)), 0.0f) * p2.z;
            float h3 = fmaxf(fmaf(p3.x, w1a, fmaf(p3.y, w1b, bb)), 0.0f) * p3.z;
            float h4 = fmaxf(fmaf(p4.x, w1a, fmaf(p4.y, w1b, bb)), 0.0f) * p4.z;
            float h5 = fmaxf(fmaf(p5.x, w1a, fmaf(p5.y, w1b, bb)), 0.0f) * p5.z;
            float h6 = fmaxf(fmaf(p6.x, w1a, fmaf(p6.y, w1b, bb)), 0.0f) * p6.z;
            float h7 = fmaxf(fmaf(p7.x, w1a, fmaf(p7.y, w1b, bb)), 0.0f) * p7.z;
            acc0 += (h0 + h1) + (h2 + h3);
            acc1 += (h4 + h5) + (h6 + h7);
        }
        for (; j + 4 <= n; j += 4) {
            v4i ra = *(const v4i*)(row + j);
            int s0 = __builtin_amdgcn_readfirstlane(ra.x);
            int s1 = __builtin_amdgcn_readfirstlane(ra.y);
            int s2 = __builtin_amdgcn_readfirstlane(ra.z);
            int s3 = __builtin_amdgcn_readfirstlane(ra.w);
            float4 p0 = zn[s0], p1 = zn[s1], p2 = zn[s2], p3 = zn[s3];
            float h0 = fmaxf(fmaf(p0.x, w1a, fmaf(p0.y, w1b, bb)), 0.0f) * p0.z;
            float h1 = fmaxf(fmaf(p1.x, w1a, fmaf(p1.y, w1b, bb)), 0.0f) * p1.z;
            float h2 = fmaxf(fmaf(p2.x, w1a, fmaf(p2.y, w1b, bb)), 0.0f) * p2.z;
            float h3 = fmaxf(fmaf(p3.x, w1a, fmaf(p3.y, w1b, bb)), 0.0f) * p3.z;
            acc0 += (h0 + h1) + (h2 + h3);
        }
        for (; j < n; ++j) {
            int s = __builtin_amdgcn_readfirstlane(row[j]);
            float4 p = zn[s];
            acc1 += fmaxf(fmaf(p.x, w1a, fmaf(p.y, w1b, bb)), 0.0f) * p.z;
        }
        float Av = (acc0 + acc1) * dv;     // lane l holds channel l's aggregate

        // FC: identical accumulation grouping to the LDS version
        // (t0 takes jj = 0,4,...,60 etc.) -> same FP result.
        float t0 = 0.0f, t1 = 0.0f, t2 = 0.0f, t3 = 0.0f;
        #pragma unroll
        for (int jj = 0; jj < 64; jj += 4) {
            t0 = fmaf(bcast_lane(Av, jj + 0), wc[jj + 0], t0);
            t1 = fmaf(bcast_lane(Av, jj + 1), wc[jj + 1], t1);
            t2 = fmaf(bcast_lane(Av, jj + 2), wc[jj + 2], t2);
            t3 = fmaf(bcast_lane(Av, jj + 3), wc[jj + 3], t3);
        }
        float t = ((t0 + t1) + (t2 + t3)) + bcl;
        out[v * 64 + l] = rintf(fmaxf(t, 0.0f));
    }
}

// ---------------- launch ----------------

extern "C" void kernel_launch(void* const* d_in, const int* in_sizes, int n_in,
                              void* d_out, int out_size, void* d_ws, size_t ws_size,
                              hipStream_t stream) {
    const float* x    = (const float*)d_in[0];
    const int*   ei   = (const int*)  d_in[1];
    const float* W1   = (const float*)d_in[2];
    const float* b1   = (const float*)d_in[3];
    const float* W2   = (const float*)d_in[4];
    const float* b2   = (const float*)d_in[5];
    const float* Wfc  = (const float*)d_in[6];
    const float* bfc  = (const float*)d_in[7];
    float* out = (float*)d_out;

    const int* src = ei;
    const int* dst = ei + N_EDGES;

    // workspace layout (bytes), 16-aligned; total 70,420,736 (unchanged)
    char* ws = (char*)d_ws;
    int*    cnt    = (int*)   (ws + 0);          //   800,000
    float4* xdc    = (float4*)(ws + 3204096);    // 3,200,000
    float4* zn     = (float4*)(ws + 6404096);    // 3,200,000
    int*    bins   = (int*)   (ws + 3204096);    // 14,680,064 (alias, dead after k_sort)
    int*    bcnt   = (int*)   (ws + 17884160);   //     2,048  (alias, dead after k_sort)
    int*    buf    = (int*)   (ws + 19204096);   // 51,200,000 padded adjacency
    float*  Wc     = (float*) (ws + 70404096);   //    16,384
    float*  bc     = (float*) (ws + 70420480);   //       256

    k_setup <<<NB_SCAN, 256, 0, stream>>>(W2, b2, Wfc, bfc, Wc, bc, bcnt);
    k_bin   <<<NB_BIN, 512, 0, stream>>>(src, dst, bins, bcnt);
    k_sort  <<<NFINE, 512, 0, stream>>>(bins, bcnt, cnt, buf);
    k_post  <<<NB_SCAN, 256, 0, stream>>>(cnt, (const float2*)x, xdc);
    k_l1a   <<<NB_SCAN, 256, 0, stream>>>(cnt, buf, xdc, zn);
    k_l2    <<<N_VAR / 16, 256, 0, stream>>>(cnt, buf, zn, W1, b1, Wc, bc, out);
}

// Round 5
// 218.296 us; speedup vs baseline: 1.1189x; 1.1189x over previous
//
#include <hip/hip_runtime.h>
#include <math.h>

#define N_NODES 200000
#define N_VAR   112000
#define N_EDGES 3200000
#define NB_SCAN 782           // ceil(200000/256)
#define CAP     64            // padded row capacity (P(deg>=64)~1e-24); == wave size

// ---- two-level counting-sort params ----
#define NFINE    512          // fine dst-range buckets
#define PSZ_F    391          // nodes per bucket (512*391 = 200192 >= 200000)
#define FCAP     7168         // per-bucket edge capacity (mean 6250, ~11.6 sigma slack)
#define BIN_CHUNK 8192        // edges per k_bin block
#define NB_BIN   391          // ceil(3.2e6/8192)

typedef int v4i __attribute__((ext_vector_type(4)));

__device__ __forceinline__ float bcast_lane(float x, int lane) {
    return __int_as_float(__builtin_amdgcn_readlane(__float_as_int(x), lane));
}

// ---------- setup: zero bcnt + fold Wc = W2@Wfc, bc ----------
__global__ void __launch_bounds__(256) k_setup(const float* __restrict__ W2,
                                               const float* __restrict__ b2,
                                               const float* __restrict__ Wfc,
                                               const float* __restrict__ bfc,
                                               float* __restrict__ Wc,
                                               float* __restrict__ bc,
                                               int* __restrict__ bcnt) {
    int b = blockIdx.x;
    int i = b * 256 + threadIdx.x;
    if (i < NFINE) bcnt[i] = 0;
    if (b < 16) {
        int e = b * 256 + threadIdx.x;     // 4096 entries
        int j = e >> 6, l = e & 63;
        double acc = 0.0;
        for (int m = 0; m < 64; ++m)
            acc += (double)W2[j * 64 + m] * (double)Wfc[m * 64 + l];
        Wc[e] = (float)acc;
    } else if (b == 16 && threadIdx.x < 64) {
        int l = threadIdx.x;
        double acc = (double)bfc[l];
        for (int m = 0; m < 64; ++m)
            acc += (double)b2[m] * (double)Wfc[m * 64 + l];
        bc[l] = (float)acc;
    }
}

// ---------- phase A: bin edges into 512 dst-range buckets ----------
// Packed entry: (dst_local<<18 | src), dst_local<391 (9b), src<2^18.
__global__ void __launch_bounds__(512) k_bin(const int* __restrict__ src,
                                             const int* __restrict__ dst,
                                             int* __restrict__ bins,
                                             int* __restrict__ bcnt) {
    __shared__ int hist[NFINE];
    __shared__ int seg[NFINE];
    __shared__ int gb[NFINE];
    __shared__ int cur[NFINE];
    __shared__ int scn[NFINE];
    __shared__ int stg[BIN_CHUNK];
    __shared__ unsigned short stgb[BIN_CHUNK];
    int tid = threadIdx.x;
    hist[tid] = 0;
    __syncthreads();

    int base = blockIdx.x * BIN_CHUNK;
    int pk[4][4];
    int bk[4][4];
    bool val[4];
    #pragma unroll
    for (int i = 0; i < 4; ++i) {
        int e4 = base + (i * 512 + tid) * 4;
        val[i] = (e4 < N_EDGES);
        if (val[i]) {
            v4i d = __builtin_nontemporal_load((const v4i*)(dst + e4));
            v4i s = __builtin_nontemporal_load((const v4i*)(src + e4));
            int dd[4] = {d.x, d.y, d.z, d.w};
            int ss[4] = {s.x, s.y, s.z, s.w};
            #pragma unroll
            for (int q = 0; q < 4; ++q) {
                int bb = dd[q] / PSZ_F;
                int dl = dd[q] - bb * PSZ_F;
                pk[i][q] = (dl << 18) | ss[q];
                bk[i][q] = bb;
                atomicAdd(&hist[bb], 1);
            }
        }
    }
    __syncthreads();

    scn[tid] = hist[tid];
    __syncthreads();
    for (int d = 1; d < NFINE; d <<= 1) {
        int t = scn[tid];
        int u = (tid >= d) ? scn[tid - d] : 0;
        __syncthreads();
        scn[tid] = t + u;
        __syncthreads();
    }
    int ex = scn[tid] - hist[tid];
    seg[tid] = ex;
    cur[tid] = ex;
    gb[tid]  = atomicAdd(&bcnt[tid], hist[tid]);
    __syncthreads();
    int tot = scn[NFINE - 1];

    #pragma unroll
    for (int i = 0; i < 4; ++i) {
        if (val[i]) {
            #pragma unroll
            for (int q = 0; q < 4; ++q) {
                int p = atomicAdd(&cur[bk[i][q]], 1);
                stg[p]  = pk[i][q];
                stgb[p] = (unsigned short)bk[i][q];
            }
        }
    }
    __syncthreads();

    for (int i = tid; i < tot; i += 512) {
        int bb  = stgb[i];
        int pos = gb[bb] + (i - seg[bb]);
        if (pos < FCAP)
            bins[(size_t)bb * FCAP + pos] = stg[i];
    }
}

// ---------- phase B: per-bucket counting sort -> exact cnt + coalesced buf rows ----------
__global__ void __launch_bounds__(512) k_sort(const int* __restrict__ bins,
                                              const int* __restrict__ bcnt,
                                              int* __restrict__ cnt,
                                              int* __restrict__ buf) {
    __shared__ int hist[NFINE];
    __shared__ int scn[NFINE];
    __shared__ int off[NFINE];
    __shared__ int cur[NFINE];
    __shared__ int sorted[FCAP];
    __shared__ unsigned short rowid[FCAP];
    int tid = threadIdx.x;
    int b = blockIdx.x;
    int n = bcnt[b];
    if (n > FCAP) n = FCAP;
    const int* __restrict__ bp = bins + (size_t)b * FCAP;

    hist[tid] = 0;
    __syncthreads();
    for (int i = tid; i < n; i += 512)
        atomicAdd(&hist[bp[i] >> 18], 1);
    __syncthreads();

    int v = b * PSZ_F + tid;
    if (tid < PSZ_F && v < N_NODES) cnt[v] = hist[tid];

    scn[tid] = hist[tid];
    __syncthreads();
    for (int d = 1; d < NFINE; d <<= 1) {
        int t = scn[tid];
        int u = (tid >= d) ? scn[tid - d] : 0;
        __syncthreads();
        scn[tid] = t + u;
        __syncthreads();
    }
    int ex = scn[tid] - hist[tid];
    off[tid] = ex;
    cur[tid] = ex;
    __syncthreads();

    for (int i = tid; i < n; i += 512) {
        int pk = bp[i];
        int dl = pk >> 18;
        int p = atomicAdd(&cur[dl], 1);
        sorted[p] = pk & 0x3FFFF;
        rowid[p]  = (unsigned short)dl;
    }
    __syncthreads();

    for (int i = tid; i < n; i += 512) {
        int dl = rowid[i];
        int slot = i - off[dl];
        if (slot < CAP)
            buf[(size_t)(b * PSZ_F + dl) * CAP + slot] = sorted[i];
    }
}

// ---------- post: xdc[v] = (xn.x, xn.y, dv, 0) ----------
__global__ void __launch_bounds__(256) k_post(const int* __restrict__ cnt,
                                              const float2* __restrict__ x2,
                                              float4* __restrict__ xdc) {
    int i = blockIdx.x * 256 + threadIdx.x;
    if (i >= N_NODES) return;
    float dv = rsqrtf((float)cnt[i] + 1.0f);
    float2 xv = x2[i];
    xdc[i] = make_float4(xv.x * dv, xv.y * dv, dv, 0.0f);
}

// ---------- layer 1: zn[v] = (i0, i1, dv, 0) -- f32 partial accumulators ----------
__global__ void __launch_bounds__(256) k_l1a(const int* __restrict__ cnt,
                                             const int* __restrict__ buf,
                                             const float4* __restrict__ xdc,
                                             float4* __restrict__ zn) {
    int v = blockIdx.x * 256 + threadIdx.x;
    if (v >= N_NODES) return;
    int c = cnt[v];
    int n = (c < CAP) ? c : CAP;
    const int* __restrict__ rowp = buf + v * CAP;
    float4 self = xdc[v];
    float dv = self.z;
    float ax = self.x, ay = self.y;
    float bx = 0.0f,   by = 0.0f;
    int j = 0;
    for (; j + 16 <= n; j += 16) {
        v4i r0 = *(const v4i*)(rowp + j);
        v4i r1 = *(const v4i*)(rowp + j + 4);
        v4i r2 = *(const v4i*)(rowp + j + 8);
        v4i r3 = *(const v4i*)(rowp + j + 12);
        float4 p0 = xdc[r0.x], p1 = xdc[r0.y], p2 = xdc[r0.z], p3 = xdc[r0.w];
        float4 p4 = xdc[r1.x], p5 = xdc[r1.y], p6 = xdc[r1.z], p7 = xdc[r1.w];
        float4 p8 = xdc[r2.x], p9 = xdc[r2.y], pa = xdc[r2.z], pb = xdc[r2.w];
        float4 pc = xdc[r3.x], pd = xdc[r3.y], pe = xdc[r3.z], pf = xdc[r3.w];
        ax += p0.x; ay += p0.y;  bx += p1.x; by += p1.y;
        ax += p2.x; ay += p2.y;  bx += p3.x; by += p3.y;
        ax += p4.x; ay += p4.y;  bx += p5.x; by += p5.y;
        ax += p6.x; ay += p6.y;  bx += p7.x; by += p7.y;
        ax += p8.x; ay += p8.y;  bx += p9.x; by += p9.y;
        ax += pa.x; ay += pa.y;  bx += pb.x; by += pb.y;
        ax += pc.x; ay += pc.y;  bx += pd.x; by += pd.y;
        ax += pe.x; ay += pe.y;  bx += pf.x; by += pf.y;
    }
    for (; j + 8 <= n; j += 8) {
        v4i r0 = *(const v4i*)(rowp + j);
        v4i r1 = *(const v4i*)(rowp + j + 4);
        float4 p0 = xdc[r0.x], p1 = xdc[r0.y], p2 = xdc[r0.z], p3 = xdc[r0.w];
        float4 p4 = xdc[r1.x], p5 = xdc[r1.y], p6 = xdc[r1.z], p7 = xdc[r1.w];
        ax += p0.x; ay += p0.y;  bx += p1.x; by += p1.y;
        ax += p2.x; ay += p2.y;  bx += p3.x; by += p3.y;
        ax += p4.x; ay += p4.y;  bx += p5.x; by += p5.y;
        ax += p6.x; ay += p6.y;  bx += p7.x; by += p7.y;
    }
    for (; j < n; ++j) {
        int s = rowp[j];
        float4 p = xdc[s];
        ax += p.x; ay += p.y;
    }
    zn[v] = make_float4((ax + bx) * dv, (ay + by) * dv, dv, 0.0f);
}

// ---------- layer 2 + folded fc, var nodes only -- all-f32, zero LDS ----------
// Aggregation: ONE per-lane gather per node (lane i fetches neighbor i's zn,
// n<=CAP=64=wave) -> all neighbor lines in flight in a single vmem instr,
// then v_readlane broadcasts (pure VALU) feed the channel math. Replaces the
// latency-serialized uniform-gather rounds (the invariant ~90us across 3 FC
// rewrites). h-expressions + accumulation tree + FC are op-identical to R4
// -> bit-identical output. __launch_bounds__(256,4): 128-VGPR budget so
// wc[64] stays in registers (R4's VGPR=44 showed it was rematerialized).
__global__ void __launch_bounds__(256, 4) k_l2(const int* __restrict__ cnt,
                                               const int* __restrict__ buf,
                                               const float4* __restrict__ zn,
                                               const float* __restrict__ W1,
                                               const float* __restrict__ b1,
                                               const float* __restrict__ Wc,
                                               const float* __restrict__ bc,
                                               float* __restrict__ out) {
    int w = threadIdx.x >> 6, l = threadIdx.x & 63;
    // per-lane Wc column: wc[j] = Wc[j][l]; 64 coalesced dword loads, once/block
    float wc[64];
    #pragma unroll
    for (int jv = 0; jv < 64; ++jv)
        wc[jv] = Wc[jv * 64 + l];
    float w1a = W1[l], w1b = W1[64 + l], bb = b1[l];
    float bcl = bc[l];
    int v0 = blockIdx.x * 16 + w;          // wave w owns v0, v0+4, v0+8, v0+12
    int cA = __builtin_amdgcn_readfirstlane(cnt[v0]);
    int cB = __builtin_amdgcn_readfirstlane(cnt[v0 + 4]);
    int cC = __builtin_amdgcn_readfirstlane(cnt[v0 + 8]);
    int cD = __builtin_amdgcn_readfirstlane(cnt[v0 + 12]);

    #pragma unroll
    for (int it = 0; it < 4; ++it) {
        int v = v0 + it * 4;
        int c = (it == 0) ? cA : (it == 1) ? cB : (it == 2) ? cC : cD;
        int n = (c < CAP) ? c : CAP;
        float dv = rsqrtf((float)c + 1.0f);
        const int* __restrict__ row = buf + v * CAP;

        // per-lane neighbor gather: lane i holds neighbor i's zn (i<n), else self
        int ridx = row[l];                 // row fully allocated (CAP ints): safe
        int idx  = (l < n) ? ridx : v;
        float4 p = zn[idx];

        float4 zs = zn[v];                 // self (uniform)
        float acc0 = fmaxf(fmaf(zs.x, w1a, fmaf(zs.y, w1b, bb)), 0.0f) * zs.z;
        float acc1 = 0.0f;
        int j = 0;
        for (; j + 8 <= n; j += 8) {
            float x0 = bcast_lane(p.x, j+0), y0 = bcast_lane(p.y, j+0), z0 = bcast_lane(p.z, j+0);
            float x1 = bcast_lane(p.x, j+1), y1 = bcast_lane(p.y, j+1), z1 = bcast_lane(p.z, j+1);
            float x2 = bcast_lane(p.x, j+2), y2 = bcast_lane(p.y, j+2), z2 = bcast_lane(p.z, j+2);
            float x3 = bcast_lane(p.x, j+3), y3 = bcast_lane(p.y, j+3), z3 = bcast_lane(p.z, j+3);
            float x4 = bcast_lane(p.x, j+4), y4 = bcast_lane(p.y, j+4), z4 = bcast_lane(p.z, j+4);
            float x5 = bcast_lane(p.x, j+5), y5 = bcast_lane(p.y, j+5), z5 = bcast_lane(p.z, j+5);
            float x6 = bcast_lane(p.x, j+6), y6 = bcast_lane(p.y, j+6), z6 = bcast_lane(p.z, j+6);
            float x7 = bcast_lane(p.x, j+7), y7 = bcast_lane(p.y, j+7), z7 = bcast_lane(p.z, j+7);
            float h0 = fmaxf(fmaf(x0, w1a, fmaf(y0, w1b, bb)), 0.0f) * z0;
            float h1 = fmaxf(fmaf(x1, w1a, fmaf(y1, w1b, bb)), 0.0f) * z1;
            float h2 = fmaxf(fmaf(x2, w1a, fmaf(y2, w1b, bb)), 0.0f) * z2;
            float h3 = fmaxf(fmaf(x3, w1a, fmaf(y3, w1b, bb)), 0.0f) * z3;
            float h4 = fmaxf(fmaf(x4, w1a, fmaf(y4, w1b, bb)), 0.0f) * z4;
            float h5 = fmaxf(fmaf(x5, w1a, fmaf(y5, w1b, bb)), 0.0f) * z5;
            float h6 = fmaxf(fmaf(x6, w1a, fmaf(y6, w1b, bb)), 0.0f) * z6;
            float h7 = fmaxf(fmaf(x7, w1a, fmaf(y7, w1b, bb)), 0.0f) * z7;
            acc0 += (h0 + h1) + (h2 + h3);
            acc1 += (h4 + h5) + (h6 + h7);
        }
        for (; j + 4 <= n; j += 4) {
            float x0 = bcast_lane(p.x, j+0), y0 = bcast_lane(p.y, j+0), z0 = bcast_lane(p.z, j+0);
            float x1 = bcast_lane(p.x, j+1), y1 = bcast_lane(p.y, j+1), z1 = bcast_lane(p.z, j+1);
            float x2 = bcast_lane(p.x, j+2), y2 = bcast_lane(p.y, j+2), z2 = bcast_lane(p.z, j+2);
            float x3 = bcast_lane(p.x, j+3), y3 = bcast_lane(p.y, j+3), z3 = bcast_lane(p.z, j+3);
            float h0 = fmaxf(fmaf(x0, w1a, fmaf(y0, w1b, bb)), 0.0f) * z0;
            float h1 = fmaxf(fmaf(x1, w1a, fmaf(y1, w1b, bb)), 0.0f) * z1;
            float h2 = fmaxf(fmaf(x2, w1a, fmaf(y2, w1b, bb)), 0.0f) * z2;
            float h3 = fmaxf(fmaf(x3, w1a, fmaf(y3, w1b, bb)), 0.0f) * z3;
            acc0 += (h0 + h1) + (h2 + h3);
        }
        for (; j < n; ++j) {
            float xk = bcast_lane(p.x, j), yk = bcast_lane(p.y, j), zk = bcast_lane(p.z, j);
            acc1 += fmaxf(fmaf(xk, w1a, fmaf(yk, w1b, bb)), 0.0f) * zk;
        }
        float Av = (acc0 + acc1) * dv;     // lane l holds channel l's aggregate

        // FC: identical accumulation grouping to R3/R4 -> same FP result.
        float t0 = 0.0f, t1 = 0.0f, t2 = 0.0f, t3 = 0.0f;
        #pragma unroll
        for (int jj = 0; jj < 64; jj += 4) {
            t0 = fmaf(bcast_lane(Av, jj + 0), wc[jj + 0], t0);
            t1 = fmaf(bcast_lane(Av, jj + 1), wc[jj + 1], t1);
            t2 = fmaf(bcast_lane(Av, jj + 2), wc[jj + 2], t2);
            t3 = fmaf(bcast_lane(Av, jj + 3), wc[jj + 3], t3);
        }
        float t = ((t0 + t1) + (t2 + t3)) + bcl;
        out[v * 64 + l] = rintf(fmaxf(t, 0.0f));
    }
}

// ---------------- launch ----------------

extern "C" void kernel_launch(void* const* d_in, const int* in_sizes, int n_in,
                              void* d_out, int out_size, void* d_ws, size_t ws_size,
                              hipStream_t stream) {
    const float* x    = (const float*)d_in[0];
    const int*   ei   = (const int*)  d_in[1];
    const float* W1   = (const float*)d_in[2];
    const float* b1   = (const float*)d_in[3];
    const float* W2   = (const float*)d_in[4];
    const float* b2   = (const float*)d_in[5];
    const float* Wfc  = (const float*)d_in[6];
    const float* bfc  = (const float*)d_in[7];
    float* out = (float*)d_out;

    const int* src = ei;
    const int* dst = ei + N_EDGES;

    // workspace layout (bytes), 16-aligned; total 70,420,736 (unchanged)
    char* ws = (char*)d_ws;
    int*    cnt    = (int*)   (ws + 0);          //   800,000
    float4* xdc    = (float4*)(ws + 3204096);    // 3,200,000
    float4* zn     = (float4*)(ws + 6404096);    // 3,200,000
    int*    bins   = (int*)   (ws + 3204096);    // 14,680,064 (alias, dead after k_sort)
    int*    bcnt   = (int*)   (ws + 17884160);   //     2,048  (alias, dead after k_sort)
    int*    buf    = (int*)   (ws + 19204096);   // 51,200,000 padded adjacency
    float*  Wc     = (float*) (ws + 70404096);   //    16,384
    float*  bc     = (float*) (ws + 70420480);   //       256

    k_setup <<<NB_SCAN, 256, 0, stream>>>(W2, b2, Wfc, bfc, Wc, bc, bcnt);
    k_bin   <<<NB_BIN, 512, 0, stream>>>(src, dst, bins, bcnt);
    k_sort  <<<NFINE, 512, 0, stream>>>(bins, bcnt, cnt, buf);
    k_post  <<<NB_SCAN, 256, 0, stream>>>(cnt, (const float2*)x, xdc);
    k_l1a   <<<NB_SCAN, 256, 0, stream>>>(cnt, buf, xdc, zn);
    k_l2    <<<N_VAR / 16, 256, 0, stream>>>(cnt, buf, zn, W1, b1, Wc, bc, out);
}